// Round 12
// baseline (14.345 us; speedup 1.0000x reference)
//
#include <hip/hip_runtime.h>
#include <hip/hip_bf16.h>

constexpr int Bn = 4096;
constexpr int Dn = 128;
constexpr int Cn = 256;

typedef __attribute__((ext_vector_type(8))) short bf16x8;  // 8 bf16 = 4 VGPR
typedef __attribute__((ext_vector_type(4))) float f32x4;

static __device__ inline unsigned short f2bfu(float f) {
    __hip_bfloat16 h = __float2bfloat16(f);
    return *reinterpret_cast<unsigned short*>(&h);
}
static __device__ inline float bfu2f(unsigned short u) {
    __hip_bfloat16 h = *reinterpret_cast<__hip_bfloat16*>(&u);
    return __bfloat162float(h);
}
static __device__ inline unsigned pk2(float x, float y) {
    return (unsigned)f2bfu(x) | ((unsigned)f2bfu(y) << 16);
}

// Byte-XOR swizzle for 256B-row bf16 tiles — AL/XL (b128 fragment reads).
#define SWZ_OFF(row, e) ((row) * 256 + ((((e) * 2)) ^ (((row) & 7) << 4)))
// Chunk-XOR layout for MD (means^T / G'): 8B chunks (4 bf16) at position q ^ (c&15).
#define MD_OFF(c, q) ((c) * 256 + ((((q) ^ ((c) & 15))) << 3))

static __device__ inline bf16x8 md_row8(const unsigned char* base, int c, int q0) {
    uint2 lo = *(const uint2*)(base + MD_OFF(c, q0));
    uint2 hi = *(const uint2*)(base + MD_OFF(c, q0 + 1));
    uint4 u;
    u.x = lo.x; u.y = lo.y; u.z = hi.x; u.w = hi.y;
    return *(bf16x8*)&u;
}

// Single fused kernel: 256 blocks x 512 threads (8 waves), block = 16 rows of X.
//   q[b,c] = x^T a x - 2 x^T (a m_c) + m_c^T (a m_c)
// Staging of alpha/means is K-CHUNKED (e in [32k,32k+32)) and software-pipelined
// against the G'-GEMM (T14: issue chunk k+1 loads before chunk-k MFMAs, write
// them to disjoint LDS after; barrier k+1 orders reads). Phases D/E/F as R11.
__global__ __launch_bounds__(512) void fused_kernel(
    const float* __restrict__ X, const float* __restrict__ means,
    const float* __restrict__ alpha, float* __restrict__ out) {
    __shared__ __align__(16) unsigned char AL[Dn * 256];  // 32KB bf16 alpha, byte-swz
    __shared__ __align__(16) unsigned char MD[Cn * 256];  // 64KB bf16 means^T -> G'
    __shared__ __align__(16) unsigned char XL[16 * 256];  // 4KB bf16 X-tile
    __shared__ float TP[2][Cn];
    __shared__ float SMIN[8][16];
    __shared__ float SXAX[8][16];

    const int tid = threadIdx.x;
    const int w = tid >> 6;
    const int lane = tid & 63;
    const int l15 = lane & 15;
    const int lh = lane >> 4;
    const int b0 = blockIdx.x * 16;
    const int cg = w & 3;
    const int rg = w >> 2;

    // per-thread chunk-staging geometry
    const int ad0 = tid >> 3;                 // alpha row for idx4 = tid
    const int ae0 = (tid & 7) << 2;           //   + e-offset within chunk
    const int ad1 = (tid + 512) >> 3;         // alpha row for idx4 = tid+512
    const int ae1 = ((tid + 512) & 7) << 2;
    const int cb = 8 * w + (lane >> 3);       // means c-block: c = 4cb..4cb+3
    const int ebl = lane & 7;                 // means e-block within chunk

    // ---------- issue X + chunk-0 loads ----------
    float4 xv = ((const float4*)(X + b0 * Dn))[tid];
    float4 a0 = *(const float4*)&alpha[ad0 * Dn + ae0];
    float4 a1 = *(const float4*)&alpha[ad1 * Dn + ae1];
    float4 m0 = *(const float4*)&means[(4 * ebl + 0) * Cn + 4 * cb];
    float4 m1 = *(const float4*)&means[(4 * ebl + 1) * Cn + 4 * cb];
    float4 m2 = *(const float4*)&means[(4 * ebl + 2) * Cn + 4 * cb];
    float4 m3 = *(const float4*)&means[(4 * ebl + 3) * Cn + 4 * cb];

    // ---------- write X + chunk-0 to LDS ----------
    {
        const int bq = tid >> 5, e0 = (tid & 31) << 2;
        uint2 pk;
        pk.x = pk2(xv.x, xv.y); pk.y = pk2(xv.z, xv.w);
        *(uint2*)(XL + SWZ_OFF(bq, e0)) = pk;
    }
    {
        unsigned char* p = AL + SWZ_OFF(ad0, ae0);
        *(unsigned*)p = pk2(a0.x, a0.y); *(unsigned*)(p + 4) = pk2(a0.z, a0.w);
        p = AL + SWZ_OFF(ad1, ae1);
        *(unsigned*)p = pk2(a1.x, a1.y); *(unsigned*)(p + 4) = pk2(a1.z, a1.w);
    }
    {
        uint2 pk;
        pk.x = pk2(m0.x, m1.x); pk.y = pk2(m2.x, m3.x);
        *(uint2*)(MD + MD_OFF(4 * cb + 0, ebl)) = pk;
        pk.x = pk2(m0.y, m1.y); pk.y = pk2(m2.y, m3.y);
        *(uint2*)(MD + MD_OFF(4 * cb + 1, ebl)) = pk;
        pk.x = pk2(m0.z, m1.z); pk.y = pk2(m2.z, m3.z);
        *(uint2*)(MD + MD_OFF(4 * cb + 2, ebl)) = pk;
        pk.x = pk2(m0.w, m1.w); pk.y = pk2(m2.w, m3.w);
        *(uint2*)(MD + MD_OFF(4 * cb + 3, ebl)) = pk;
    }

    // ---------- pipelined Phase C: chunk k0 MFMA || chunk k0+1 staging ----------
    f32x4 gacc[4][4];
    #pragma unroll
    for (int j = 0; j < 4; ++j)
        #pragma unroll
        for (int s = 0; s < 4; ++s) gacc[j][s] = (f32x4){0.f, 0.f, 0.f, 0.f};
    f32x4 xacc = (f32x4){0.f, 0.f, 0.f, 0.f};
    bf16x8 af[4];

    #pragma unroll
    for (int k0 = 0; k0 < 4; ++k0) {
        __syncthreads();   // chunk k0 staged (and prev writes ordered)

        // prefetch chunk k0+1 (global loads — hide under MFMAs below)
        float4 na0, na1, nm0, nm1, nm2, nm3;
        if (k0 < 3) {
            const int ke = 32 * (k0 + 1);
            na0 = *(const float4*)&alpha[ad0 * Dn + ke + ae0];
            na1 = *(const float4*)&alpha[ad1 * Dn + ke + ae1];
            const int eb = 8 * (k0 + 1) + ebl;
            nm0 = *(const float4*)&means[(4 * eb + 0) * Cn + 4 * cb];
            nm1 = *(const float4*)&means[(4 * eb + 1) * Cn + 4 * cb];
            nm2 = *(const float4*)&means[(4 * eb + 2) * Cn + 4 * cb];
            nm3 = *(const float4*)&means[(4 * eb + 3) * Cn + 4 * cb];
        }

        // MFMA on chunk k0 (identical math to R11)
        af[k0] = *(const bf16x8*)(XL + SWZ_OFF(l15, 32 * k0 + 8 * lh));
        bf16x8 bj[4];
        #pragma unroll
        for (int j = 0; j < 4; ++j) {
            const int c = 64 * cg + 16 * j + l15;
            bj[j] = md_row8(MD, c, 8 * k0 + 2 * lh);
        }
        #pragma unroll
        for (int s = 0; s < 4; ++s) {
            const int mt = 4 * rg + s;
            bf16x8 a = *(const bf16x8*)(AL + SWZ_OFF(16 * mt + l15, 32 * k0 + 8 * lh));
            #pragma unroll
            for (int j = 0; j < 4; ++j)
                gacc[j][s] = __builtin_amdgcn_mfma_f32_16x16x32_bf16(a, bj[j], gacc[j][s], 0, 0, 0);
        }
        {
            bf16x8 aH = *(const bf16x8*)(AL + SWZ_OFF(16 * w + l15, 32 * k0 + 8 * lh));
            xacc = __builtin_amdgcn_mfma_f32_16x16x32_bf16(aH, af[k0], xacc, 0, 0, 0);
        }

        // write chunk k0+1 to LDS (disjoint from chunk-k0 reads; next barrier orders)
        if (k0 < 3) {
            const int ke = 32 * (k0 + 1);
            unsigned char* p = AL + SWZ_OFF(ad0, ke + ae0);
            *(unsigned*)p = pk2(na0.x, na0.y); *(unsigned*)(p + 4) = pk2(na0.z, na0.w);
            p = AL + SWZ_OFF(ad1, ke + ae1);
            *(unsigned*)p = pk2(na1.x, na1.y); *(unsigned*)(p + 4) = pk2(na1.z, na1.w);
            const int eb = 8 * (k0 + 1) + ebl;
            uint2 pk;
            pk.x = pk2(nm0.x, nm1.x); pk.y = pk2(nm2.x, nm3.x);
            *(uint2*)(MD + MD_OFF(4 * cb + 0, eb)) = pk;
            pk.x = pk2(nm0.y, nm1.y); pk.y = pk2(nm2.y, nm3.y);
            *(uint2*)(MD + MD_OFF(4 * cb + 1, eb)) = pk;
            pk.x = pk2(nm0.z, nm1.z); pk.y = pk2(nm2.z, nm3.z);
            *(uint2*)(MD + MD_OFF(4 * cb + 2, eb)) = pk;
            pk.x = pk2(nm0.w, nm1.w); pk.y = pk2(nm2.w, nm3.w);
            *(uint2*)(MD + MD_OFF(4 * cb + 3, eb)) = pk;
        }
    }

    // xax partial: lane (b=l15, lh) holds H[16w+4lh+r][b]; dot with x[b][same d]
    {
        uint2 pk = *(const uint2*)(XL + SWZ_OFF(l15, 16 * w + 4 * lh));
        float v = bfu2f((unsigned short)(pk.x & 0xffffu)) * xacc[0];
        v = fmaf(bfu2f((unsigned short)(pk.x >> 16)),     xacc[1], v);
        v = fmaf(bfu2f((unsigned short)(pk.y & 0xffffu)), xacc[2], v);
        v = fmaf(bfu2f((unsigned short)(pk.y >> 16)),     xacc[3], v);
        v += __shfl_xor(v, 16);
        v += __shfl_xor(v, 32);
        if (lane < 16) SXAX[w][lane] = v;
    }

    // ---------- Phase D: partial t[c] over this wave's d-half ----------
    {
        float tpart[4];
        #pragma unroll
        for (int j = 0; j < 4; ++j) {
            const int c = 64 * cg + 16 * j + l15;
            float v = 0.f;
            #pragma unroll
            for (int s = 0; s < 4; ++s) {
                const int mt = 4 * rg + s;
                uint2 mm = *(const uint2*)(MD + MD_OFF(c, 4 * mt + lh));
                v = fmaf(bfu2f((unsigned short)(mm.x & 0xffffu)), gacc[j][s][0], v);
                v = fmaf(bfu2f((unsigned short)(mm.x >> 16)),     gacc[j][s][1], v);
                v = fmaf(bfu2f((unsigned short)(mm.y & 0xffffu)), gacc[j][s][2], v);
                v = fmaf(bfu2f((unsigned short)(mm.y >> 16)),     gacc[j][s][3], v);
            }
            v += __shfl_xor(v, 16);
            v += __shfl_xor(v, 32);
            tpart[j] = v;
        }
        if (lane < 16)
            #pragma unroll
            for (int j = 0; j < 4; ++j) TP[rg][64 * cg + 16 * j + lane] = tpart[j];
    }
    __syncthreads();   // all means-reads (C/D) complete before E overwrites

    // ---------- Phase E: overwrite MD with G' ----------
    #pragma unroll
    for (int j = 0; j < 4; ++j) {
        const int c = 64 * cg + 16 * j + l15;
        #pragma unroll
        for (int s = 0; s < 4; ++s) {
            const int mt = 4 * rg + s;
            uint2 pk;
            pk.x = pk2(gacc[j][s][0], gacc[j][s][1]);
            pk.y = pk2(gacc[j][s][2], gacc[j][s][3]);
            *(uint2*)(MD + MD_OFF(c, 4 * mt + lh)) = pk;
        }
    }
    __syncthreads();

    // ---------- Phase F: S' = X*G' -- wave w: tiles 2w, 2w+1 (af reused) ----------
    bf16x8 bf2[2][4];
    #pragma unroll
    for (int j2 = 0; j2 < 2; ++j2) {
        const int rowc = 16 * (2 * w + j2) + l15;
        #pragma unroll
        for (int k0 = 0; k0 < 4; ++k0)
            bf2[j2][k0] = md_row8(MD, rowc, 8 * k0 + 2 * lh);
    }
    f32x4 macc[2];
    #pragma unroll
    for (int j2 = 0; j2 < 2; ++j2) macc[j2] = (f32x4){0.f, 0.f, 0.f, 0.f};
    #pragma unroll
    for (int k0 = 0; k0 < 4; ++k0)
        #pragma unroll
        for (int j2 = 0; j2 < 2; ++j2)
            macc[j2] = __builtin_amdgcn_mfma_f32_16x16x32_bf16(af[k0], bf2[j2][k0], macc[j2], 0, 0, 0);

    // epilogue
    {
        float mr[4];
        #pragma unroll
        for (int r = 0; r < 4; ++r) mr[r] = 1e30f;
        #pragma unroll
        for (int j2 = 0; j2 < 2; ++j2) {
            const int c = 16 * (2 * w + j2) + l15;
            const float tc = TP[0][c] + TP[1][c];
            #pragma unroll
            for (int r = 0; r < 4; ++r)
                mr[r] = fminf(mr[r], tc - 2.f * macc[j2][r]);
        }
        #pragma unroll
        for (int r = 0; r < 4; ++r) {
            #pragma unroll
            for (int m = 1; m < 16; m <<= 1)
                mr[r] = fminf(mr[r], __shfl_xor(mr[r], m));
        }
        if (l15 == 0)
            #pragma unroll
            for (int r = 0; r < 4; ++r) SMIN[w][4 * lh + r] = mr[r];
    }
    __syncthreads();

    if (tid < 16) {
        float mnv = 1e30f, xa = 0.f;
        #pragma unroll
        for (int w8 = 0; w8 < 8; ++w8) {
            mnv = fminf(mnv, SMIN[w8][tid]);
            xa += SXAX[w8][tid];
        }
        out[b0 + tid] = xa + mnv;
    }
}

extern "C" void kernel_launch(void* const* d_in, const int* in_sizes, int n_in,
                              void* d_out, int out_size, void* d_ws, size_t ws_size,
                              hipStream_t stream) {
    const float* X     = (const float*)d_in[0];
    const float* means = (const float*)d_in[1];
    const float* alpha = (const float*)d_in[2];
    float* out = (float*)d_out;
    fused_kernel<<<Bn / 16, 512, 0, stream>>>(X, means, alpha, out);
}

// Round 13
// 11.493 us; speedup vs baseline: 1.2481x; 1.2481x over previous
//
#include <hip/hip_runtime.h>
#include <hip/hip_bf16.h>

constexpr int Bn = 4096;
constexpr int Dn = 128;
constexpr int Cn = 256;

typedef __attribute__((ext_vector_type(8))) short bf16x8;  // 8 bf16 = 4 VGPR
typedef __attribute__((ext_vector_type(4))) float f32x4;

static __device__ inline unsigned short f2bfu(float f) {
    __hip_bfloat16 h = __float2bfloat16(f);
    return *reinterpret_cast<unsigned short*>(&h);
}
static __device__ inline float bfu2f(unsigned short u) {
    __hip_bfloat16 h = *reinterpret_cast<__hip_bfloat16*>(&u);
    return __bfloat162float(h);
}
static __device__ inline unsigned pk2(float x, float y) {
    return (unsigned)f2bfu(x) | ((unsigned)f2bfu(y) << 16);
}

// Byte-XOR swizzle for 256B-row bf16 tiles — used by AL/XL (b128 fragment reads).
#define SWZ_OFF(row, e) ((row) * 256 + ((((e) * 2)) ^ (((row) & 7) << 4)))
// Chunk-XOR layout for MD (means^T / G'): 8B chunks (4 bf16), chunk q = d/4 stored
// at position q ^ (c&15). All 8B accesses at (c=..+l15, q=f(lh)) are conflict-free.
#define MD_OFF(c, q) ((c) * 256 + ((((q) ^ ((c) & 15))) << 3))

static __device__ inline bf16x8 md_row8(const unsigned char* base, int c, int q0) {
    // 8 consecutive-d bf16 (chunks q0, q0+1) of row c
    uint2 lo = *(const uint2*)(base + MD_OFF(c, q0));
    uint2 hi = *(const uint2*)(base + MD_OFF(c, q0 + 1));
    uint4 u;
    u.x = lo.x; u.y = lo.y; u.z = hi.x; u.w = hi.y;
    return *(bf16x8*)&u;
}

// Single fused kernel: 256 blocks x 512 threads (8 waves), block = 16 rows of X.
//   q[b,c] = x^T a x - 2 x^T (a m_c) + m_c^T (a m_c)
// Phase C: G' = a*means (4col x 4row tiles/wave) + H-tile (a*X^T) with B = af
// Phase D: partial t[c] over wave's d-half -> TP[rg][c]  (fp32)
// Phase E: overwrite MD with bf16 G' (same chunk layout)
// Phase F: S' = X*G' (2 tiles/wave, af reused), min epilogue t = TP[0]+TP[1].
// NOTE (R12 lesson): keep ONE barrier between staging and compute — explicit
// K-chunk pipelining with per-chunk barriers regressed 11.5 -> 14.3 µs (the
// CU's implicit cross-wave overlap beats lock-step software pipelining here).
__global__ __launch_bounds__(512) void fused_kernel(
    const float* __restrict__ X, const float* __restrict__ means,
    const float* __restrict__ alpha, float* __restrict__ out) {
    __shared__ __align__(16) unsigned char AL[Dn * 256];  // 32KB: bf16 alpha, byte-swizzled
    __shared__ __align__(16) unsigned char MD[Cn * 256];  // 64KB: bf16 means^T; later G' (chunk-XOR)
    __shared__ __align__(16) unsigned char XL[16 * 256];  // 4KB:  bf16 X-tile, byte-swizzled
    __shared__ float TP[2][Cn];                            // 2KB: t partials per d-half
    __shared__ float SMIN[8][16];
    __shared__ float SXAX[8][16];

    const int tid = threadIdx.x;
    const int w = tid >> 6;          // wave 0..7
    const int lane = tid & 63;
    const int l15 = lane & 15;
    const int lh = lane >> 4;        // 0..3
    const int b0 = blockIdx.x * 16;
    const int cg = w & 3;            // col-group: cols 64cg..64cg+63
    const int rg = w >> 2;           // row-group: d in [64rg, 64rg+64)

    // ---------- Phase A: stage X-tile, alpha (byte-swz), means^T (chunk-XOR) ----------
    {
        {
            float4 v = ((const float4*)(X + b0 * Dn))[tid];
            const int b = tid >> 5;
            const int e0 = (tid & 31) << 2;
            uint2 pk;
            pk.x = pk2(v.x, v.y); pk.y = pk2(v.z, v.w);
            *(uint2*)(XL + SWZ_OFF(b, e0)) = pk;
        }
        const float4* a4 = (const float4*)alpha;
        #pragma unroll
        for (int i = 0; i < 8; ++i) {
            int idx4 = tid + i * 512;
            int d = idx4 >> 5, e0 = (idx4 & 31) << 2;
            float4 v = a4[idx4];
            unsigned char* p = AL + SWZ_OFF(d, e0);
            *(unsigned*)p = pk2(v.x, v.y);
            *(unsigned*)(p + 4) = pk2(v.z, v.w);
        }
        // means^T via 4x4 register transpose into chunk-XOR MD
        const int cb = 8 * w + (lane & 7);       // c = 4cb..4cb+3
        const int db0 = lane >> 3;               // 0..7
        #pragma unroll
        for (int i = 0; i < 4; ++i) {
            const int db = db0 + 8 * i;          // chunk q = db; d = 4db..4db+3
            float4 v0 = *(const float4*)&means[(4 * db + 0) * Cn + 4 * cb];
            float4 v1 = *(const float4*)&means[(4 * db + 1) * Cn + 4 * cb];
            float4 v2 = *(const float4*)&means[(4 * db + 2) * Cn + 4 * cb];
            float4 v3 = *(const float4*)&means[(4 * db + 3) * Cn + 4 * cb];
            uint2 pk;
            pk.x = pk2(v0.x, v1.x); pk.y = pk2(v2.x, v3.x);
            *(uint2*)(MD + MD_OFF(4 * cb + 0, db)) = pk;
            pk.x = pk2(v0.y, v1.y); pk.y = pk2(v2.y, v3.y);
            *(uint2*)(MD + MD_OFF(4 * cb + 1, db)) = pk;
            pk.x = pk2(v0.z, v1.z); pk.y = pk2(v2.z, v3.z);
            *(uint2*)(MD + MD_OFF(4 * cb + 2, db)) = pk;
            pk.x = pk2(v0.w, v1.w); pk.y = pk2(v2.w, v3.w);
            *(uint2*)(MD + MD_OFF(4 * cb + 3, db)) = pk;
        }
    }
    __syncthreads();

    // ---------- Phase C: G' GEMM (4col x 4row) + H-tile + af hoist ----------
    f32x4 gacc[4][4];                 // [col-tile j][row-tile s: mt = 4rg+s]
    #pragma unroll
    for (int j = 0; j < 4; ++j)
        #pragma unroll
        for (int s = 0; s < 4; ++s) gacc[j][s] = (f32x4){0.f, 0.f, 0.f, 0.f};
    f32x4 xacc = (f32x4){0.f, 0.f, 0.f, 0.f};
    bf16x8 af[4];                     // XL row l15 — B for H-tile AND A for Phase F

    #pragma unroll
    for (int k0 = 0; k0 < 4; ++k0) {
        af[k0] = *(const bf16x8*)(XL + SWZ_OFF(l15, 32 * k0 + 8 * lh));
        bf16x8 bj[4];
        #pragma unroll
        for (int j = 0; j < 4; ++j) {
            const int c = 64 * cg + 16 * j + l15;
            bj[j] = md_row8(MD, c, 8 * k0 + 2 * lh);   // 2 conflict-free b64
        }
        #pragma unroll
        for (int s = 0; s < 4; ++s) {
            const int mt = 4 * rg + s;
            bf16x8 a = *(const bf16x8*)(AL + SWZ_OFF(16 * mt + l15, 32 * k0 + 8 * lh));
            #pragma unroll
            for (int j = 0; j < 4; ++j)
                gacc[j][s] = __builtin_amdgcn_mfma_f32_16x16x32_bf16(a, bj[j], gacc[j][s], 0, 0, 0);
        }
        // H-tile rows 16w..16w+15: C[d][b] = sum_e a[d][e] X[b][e]; B = af (X rows)
        {
            bf16x8 aH = *(const bf16x8*)(AL + SWZ_OFF(16 * w + l15, 32 * k0 + 8 * lh));
            xacc = __builtin_amdgcn_mfma_f32_16x16x32_bf16(aH, af[k0], xacc, 0, 0, 0);
        }
    }

    // xax partial: lane (b=l15, lh) holds H[16w+4lh+r][b]; dot with x[b][same d]
    {
        uint2 pk = *(const uint2*)(XL + SWZ_OFF(l15, 16 * w + 4 * lh));
        float v = bfu2f((unsigned short)(pk.x & 0xffffu)) * xacc[0];
        v = fmaf(bfu2f((unsigned short)(pk.x >> 16)),     xacc[1], v);
        v = fmaf(bfu2f((unsigned short)(pk.y & 0xffffu)), xacc[2], v);
        v = fmaf(bfu2f((unsigned short)(pk.y >> 16)),     xacc[3], v);
        v += __shfl_xor(v, 16);
        v += __shfl_xor(v, 32);
        if (lane < 16) SXAX[w][lane] = v;
    }

    // ---------- Phase D: partial t[c] over this wave's d-half (conflict-free b64) ----------
    {
        float tpart[4];
        #pragma unroll
        for (int j = 0; j < 4; ++j) {
            const int c = 64 * cg + 16 * j + l15;
            float v = 0.f;
            #pragma unroll
            for (int s = 0; s < 4; ++s) {
                const int mt = 4 * rg + s;
                uint2 mm = *(const uint2*)(MD + MD_OFF(c, 4 * mt + lh));
                v = fmaf(bfu2f((unsigned short)(mm.x & 0xffffu)), gacc[j][s][0], v);
                v = fmaf(bfu2f((unsigned short)(mm.x >> 16)),     gacc[j][s][1], v);
                v = fmaf(bfu2f((unsigned short)(mm.y & 0xffffu)), gacc[j][s][2], v);
                v = fmaf(bfu2f((unsigned short)(mm.y >> 16)),     gacc[j][s][3], v);
            }
            v += __shfl_xor(v, 16);   // reduce over lh (butterfly, all lanes get sum)
            v += __shfl_xor(v, 32);
            tpart[j] = v;
        }
        if (lane < 16)
            #pragma unroll
            for (int j = 0; j < 4; ++j) TP[rg][64 * cg + 16 * j + lane] = tpart[j];
    }
    __syncthreads();   // other waves' C/D means-reads (full d-range) before E writes

    // ---------- Phase E: overwrite MD with G' (this wave's (c, d-half) slots) ----------
    #pragma unroll
    for (int j = 0; j < 4; ++j) {
        const int c = 64 * cg + 16 * j + l15;
        #pragma unroll
        for (int s = 0; s < 4; ++s) {
            const int mt = 4 * rg + s;
            uint2 pk;
            pk.x = pk2(gacc[j][s][0], gacc[j][s][1]);
            pk.y = pk2(gacc[j][s][2], gacc[j][s][3]);
            *(uint2*)(MD + MD_OFF(c, 4 * mt + lh)) = pk;
        }
    }
    __syncthreads();

    // ---------- Phase F: S' = X*G' -- wave w: tiles 2w, 2w+1 of 16 (af reused) ----------
    bf16x8 bf2[2][4];
    #pragma unroll
    for (int j2 = 0; j2 < 2; ++j2) {
        const int rowc = 16 * (2 * w + j2) + l15;
        #pragma unroll
        for (int k0 = 0; k0 < 4; ++k0)
            bf2[j2][k0] = md_row8(MD, rowc, 8 * k0 + 2 * lh);
    }
    f32x4 macc[2];
    #pragma unroll
    for (int j2 = 0; j2 < 2; ++j2) macc[j2] = (f32x4){0.f, 0.f, 0.f, 0.f};
    #pragma unroll
    for (int k0 = 0; k0 < 4; ++k0)
        #pragma unroll
        for (int j2 = 0; j2 < 2; ++j2)
            macc[j2] = __builtin_amdgcn_mfma_f32_16x16x32_bf16(af[k0], bf2[j2][k0], macc[j2], 0, 0, 0);

    // epilogue: C layout col=l15 (=c within tile), row=4lh+reg (=b)
    {
        float mr[4];
        #pragma unroll
        for (int r = 0; r < 4; ++r) mr[r] = 1e30f;
        #pragma unroll
        for (int j2 = 0; j2 < 2; ++j2) {
            const int c = 16 * (2 * w + j2) + l15;
            const float tc = TP[0][c] + TP[1][c];
            #pragma unroll
            for (int r = 0; r < 4; ++r)
                mr[r] = fminf(mr[r], tc - 2.f * macc[j2][r]);   // -2 x^T (a m_c)
        }
        #pragma unroll
        for (int r = 0; r < 4; ++r) {
            #pragma unroll
            for (int m = 1; m < 16; m <<= 1)
                mr[r] = fminf(mr[r], __shfl_xor(mr[r], m));
        }
        if (l15 == 0)
            #pragma unroll
            for (int r = 0; r < 4; ++r) SMIN[w][4 * lh + r] = mr[r];
    }
    __syncthreads();

    if (tid < 16) {
        float mnv = 1e30f, xa = 0.f;
        #pragma unroll
        for (int w8 = 0; w8 < 8; ++w8) {
            mnv = fminf(mnv, SMIN[w8][tid]);
            xa += SXAX[w8][tid];
        }
        out[b0 + tid] = xa + mnv;   // xa = x^T a x
    }
}

extern "C" void kernel_launch(void* const* d_in, const int* in_sizes, int n_in,
                              void* d_out, int out_size, void* d_ws, size_t ws_size,
                              hipStream_t stream) {
    const float* X     = (const float*)d_in[0];
    const float* means = (const float*)d_in[1];
    const float* alpha = (const float*)d_in[2];
    float* out = (float*)d_out;
    fused_kernel<<<Bn / 16, 512, 0, stream>>>(X, means, alpha, out);
}